// Round 3
// baseline (180.339 us; speedup 1.0000x reference)
//
#include <hip/hip_runtime.h>
#include <hip/hip_cooperative_groups.h>

namespace cg = cooperative_groups;

typedef unsigned long long u64;
typedef unsigned int u32;

#define HW 65536            // 256*256 attention positions per batch
#define NB 8                // batch
#define NSEL 16             // top-k
#define NC 3
#define HH 2048             // x_high H=W
#define NCHUNK 256          // 256-elem chunks per batch
#define CAP 1024            // candidate buffer per batch

// surrogate key: order(log a - log(-log u)) == order(a / (-log2 u)).
// Single shared definition -> both passes compute bit-identical w.
__device__ __forceinline__ u32 wkey(float a, float u) {
  float v = __builtin_amdgcn_logf(u);            // log2(u) < 0
  float w = a * __builtin_amdgcn_rcpf(-v);       // a / (-log2 u) > 0
  return __float_as_uint(w);                     // positive floats order as uints
}

__device__ __forceinline__ u32 wave_max_u32(u32 k) {
#pragma unroll
  for (int off = 1; off < 64; off <<= 1) {
    u32 o = __shfl_xor(k, off, 64);
    k = (o > k) ? o : k;
  }
  return k;
}

__device__ __forceinline__ u64 wave_max64(u64 k) {
#pragma unroll
  for (int off = 1; off < 64; off <<= 1) {
    u32 lo = __shfl_xor((u32)k, off, 64);
    u32 hi = __shfl_xor((u32)(k >> 32), off, 64);
    u64 o = ((u64)hi << 32) | lo;
    if (o > k) k = o;
  }
  return k;
}

// One cooperative kernel: 512 blocks x 256 threads (64 blocks per batch).
__global__ __launch_bounds__(256) void fused_sample_patches(
    const float* __restrict__ xh, const float* __restrict__ att,
    const float* __restrict__ noise, float* __restrict__ out,
    float* __restrict__ att_out, u32* __restrict__ cmax,
    u32* __restrict__ cnt, u64* __restrict__ cand) {
  const int tid = threadIdx.x;
  const int lane = tid & 63;
  const int wave = tid >> 6;
  const int b = blockIdx.x >> 6;       // batch
  const int blk = blockIdx.x & 63;     // block within batch (1024 elems each)
  __shared__ int s_idx[NSEL];

  // ---------- phase 1: per-wave 256-elem chunk max ----------
  if (blockIdx.x == 0 && tid < NB) cnt[tid] = 0;
  {
    const int base = b * HW + blk * 1024 + wave * 256;
    u32 best = 0;
#pragma unroll
    for (int k = 0; k < 4; k++) {
      const int i = base + (k << 6) + lane;     // coalesced
      best = max(best, wkey(att[i], noise[i]));
    }
    best = wave_max_u32(best);
    if (lane == 0) cmax[b * NCHUNK + (blk << 2) + wave] = best;
  }
  __threadfence();
  cg::this_grid().sync();

  // ---------- phase 2: threshold T + filter + append ----------
  {
    // every wave redundantly reduces the 256 chunk-maxes -> T
    u32 k4[4];
#pragma unroll
    for (int j = 0; j < 4; j++) {
      u32 v = cmax[b * NCHUNK + (j << 6) + lane];
      k4[j] = v;
#pragma unroll
      for (int i = 3; i > 0; i--) {
        if (i <= j && k4[i] > k4[i - 1]) { u32 t = k4[i - 1]; k4[i - 1] = k4[i]; k4[i] = t; }
      }
    }
    u32 T = 0;
#pragma unroll
    for (int r = 0; r < NSEL; r++) {
      u32 g = wave_max_u32(k4[0]);
      T = g;
      if (k4[0] == g) { k4[0] = k4[1]; k4[1] = k4[2]; k4[2] = k4[3]; k4[3] = 0; }
    }

    const int ebase = b * HW + blk * 1024;
#pragma unroll
    for (int k = 0; k < 4; k++) {
      const int gi = ebase + (k << 8) + tid;
      u32 w = wkey(att[gi], noise[gi]);
      if (w >= T) {
        u32 pos = atomicAdd(&cnt[b], 1u);       // device-scope
        if (pos < CAP) {
          u32 e = (u32)(gi - b * HW);
          cand[b * CAP + pos] = ((u64)w << 32) | (0xFFFFFFFFu - e);
        }
      }
    }
  }
  __threadfence();
  cg::this_grid().sync();

  // ---------- phase 3: redundant per-block final top-16 (wave 0) ----------
  if (wave == 0) {
    int n = (int)cnt[b]; if (n > CAP) n = CAP;
    u64 keys[NSEL];
#pragma unroll
    for (int i = 0; i < NSEL; i++) keys[i] = 0ULL;
    for (int i = lane; i < n; i += 64) {
      u64 kk = cand[b * CAP + i];
#pragma unroll
      for (int j = 0; j < NSEL; j++) {
        if (kk > keys[j]) { u64 t = keys[j]; keys[j] = kk; kk = t; }
      }
    }
    u64 won = 0ULL;
#pragma unroll
    for (int r = 0; r < NSEL; r++) {
      u64 g = wave_max64(keys[0]);
      if (lane == r) won = g;
      if (keys[0] == g) {
#pragma unroll
        for (int i = 0; i < NSEL - 1; i++) keys[i] = keys[i + 1];
        keys[NSEL - 1] = 0ULL;
      }
    }
    if (lane < NSEL) {
      u32 e = 0xFFFFFFFFu - (u32)(won & 0xFFFFFFFFu);
      s_idx[lane] = (int)e;
      if (blk == 0) att_out[b * NSEL + lane] = att[b * HW + (int)e];  // bit-exact gather
    }
  }
  __syncthreads();

  // ---------- phase 4: patch extraction (this block's 3072 float4) ----------
  float4* out4 = (float4*)out;
#pragma unroll
  for (int it = 0; it < 12; it++) {
    const int fi = blk * 3072 + it * 256 + tid;   // within-batch float4 idx [0,196608)
    const int pc = fi >> 12;                      // channel-patch 0..47
    const int n = pc / 3;                         // patch 0..15
    const int c = pc - n * 3;                     // channel 0..2
    const int r = (fi >> 5) & 127;                // row in patch
    const int q = fi & 31;                        // float4 in row
    const int e = s_idx[n];
    const int row = (e >> 8) * 8 - 60 + r;
    const int col = (e & 255) * 8 - 60 + (q << 2);
    float4 v = make_float4(0.f, 0.f, 0.f, 0.f);
    // col is a multiple of 4, so a float4 group is fully in-bounds or fully out
    if ((u32)row < (u32)HH && (u32)col < (u32)HH) {
      v = *reinterpret_cast<const float4*>(
          xh + (((size_t)(b * NC + c)) << 22) + ((size_t)row << 11) + col);
    }
    out4[(size_t)b * 196608 + fi] = v;
  }
}

extern "C" void kernel_launch(void* const* d_in, const int* in_sizes, int n_in,
                              void* d_out, int out_size, void* d_ws, size_t ws_size,
                              hipStream_t stream) {
  (void)in_sizes; (void)n_in; (void)out_size; (void)ws_size;
  // inputs: 0=x_low (unused, shape-only), 1=x_high, 2=attention, 3=noise_u
  const float* x_high = (const float*)d_in[1];
  const float* att    = (const float*)d_in[2];
  const float* noise  = (const float*)d_in[3];
  float* out = (float*)d_out;
  float* att_out = out + (size_t)NB * NSEL * NC * 128 * 128;   // 6291456

  char* ws = (char*)d_ws;
  u32* cmax = (u32*)ws;                                        // 8*256*4 = 8 KiB
  u32* cnt  = (u32*)(ws + NB * NCHUNK * 4);                    // 8 u32
  u64* cand = (u64*)(ws + NB * NCHUNK * 4 + 256);              // 8*1024*8 = 64 KiB

  void* args[] = {(void*)&x_high, (void*)&att, (void*)&noise, (void*)&out,
                  (void*)&att_out, (void*)&cmax, (void*)&cnt, (void*)&cand};
  hipLaunchCooperativeKernel((const void*)fused_sample_patches,
                             dim3(NB * 64), dim3(256), args, 0, stream);
}

// Round 4
// 89.495 us; speedup vs baseline: 2.0151x; 2.0151x over previous
//
#include <hip/hip_runtime.h>

typedef unsigned long long u64;
typedef unsigned int u32;

#define HW 65536            // 256*256 attention positions per batch
#define NB 8                // batch
#define NSEL 16             // top-k
#define NC 3
#define HH 2048             // x_high H=W

// surrogate key: order(log a - log(-log u)) == order(a / (-log2 u)).
__device__ __forceinline__ u32 wkey(float a, float u) {
  float v = __builtin_amdgcn_logf(u);            // log2(u) < 0
  float w = a * __builtin_amdgcn_rcpf(-v);       // a / (-log2 u) > 0
  return __float_as_uint(w);                     // positive floats order as uints
}

__device__ __forceinline__ u64 wave_max64(u64 k) {
#pragma unroll
  for (int off = 1; off < 64; off <<= 1) {
    u32 lo = __shfl_xor((u32)k, off, 64);
    u32 hi = __shfl_xor((u32)(k >> 32), off, 64);
    u64 o = ((u64)hi << 32) | lo;
    if (o > k) k = o;
  }
  return k;
}

#define CMPSWAP(a, b) { if ((b) > (a)) { u64 t_ = (a); (a) = (b); (b) = t_; } }

// Single fused kernel: 512 blocks x 256 threads (64 blocks/batch, 2 blocks/CU,
// all co-resident -> hand-rolled per-batch spin barrier is deadlock-free).
__global__ __launch_bounds__(256, 2) void fused_sample_patches(
    const float* __restrict__ xh, const float* __restrict__ att,
    const float* __restrict__ noise, float* __restrict__ out,
    float* __restrict__ att_out, u64* __restrict__ cand,
    u32* __restrict__ bar) {
  const int tid = threadIdx.x;
  const int lane = tid & 63;
  const int wave = tid >> 6;
  const int b = blockIdx.x >> 6;       // batch
  const int blk = blockIdx.x & 63;     // block within batch (1024 elems)

  __shared__ u64 s_wtop[64];           // 4 waves x 16
  __shared__ int s_idx[NSEL];

  // ---- A1: per-lane sorted-4 of its 4 elements ----
  const int ebase = blk * 1024 + wave * 256;   // within-batch element base
  u64 k4[4];
#pragma unroll
  for (int j = 0; j < 4; j++) {
    const int e = ebase + (j << 6) + lane;     // coalesced
    const int gi = b * HW + e;
    k4[j] = ((u64)wkey(att[gi], noise[gi]) << 32) | (0xFFFFFFFFu - (u32)e);
  }
  // descending sort-4 network
  CMPSWAP(k4[0], k4[1]); CMPSWAP(k4[2], k4[3]);
  CMPSWAP(k4[0], k4[2]); CMPSWAP(k4[1], k4[3]);
  CMPSWAP(k4[1], k4[2]);

  // ---- A2: per-wave top-16 -> LDS (16 extraction rounds) ----
#pragma unroll
  for (int r = 0; r < NSEL; r++) {
    u64 g = wave_max64(k4[0]);
    if (k4[0] == g) {                  // keys globally distinct -> unique winner
      s_wtop[wave * 16 + r] = g;
      k4[0] = k4[1]; k4[1] = k4[2]; k4[2] = k4[3]; k4[3] = 0ULL;
    }
  }
  __syncthreads();

  // ---- A3: wave 0 merges 64 -> sorted block top-16 -> global cand ----
  if (wave == 0) {
    u64 kk = s_wtop[lane];
#pragma unroll
    for (int r = 0; r < NSEL; r++) {
      u64 g = wave_max64(kk);
      if (kk == g) {
        cand[(size_t)blockIdx.x * NSEL + r] = g;   // sorted position r
        kk = 0ULL;
      }
    }
  }
  __syncthreads();

  // ---- per-batch arrival barrier (64 blocks) ----
  if (tid == 0) {
    __threadfence();                   // release our cand writes (device scope)
    atomicAdd(&bar[b], 1u);
    while (__hip_atomic_load(&bar[b], __ATOMIC_ACQUIRE, __HIP_MEMORY_SCOPE_AGENT) < 64u) {
      __builtin_amdgcn_s_sleep(2);
    }
  }
  __syncthreads();
  __threadfence();                     // acquire side: invalidate stale caches

  // ---- final merge (wave 0, redundant per block): 64 sorted 16-lists ----
  if (wave == 0) {
    const u64* cb = cand + (size_t)(b * 64 + lane) * NSEL;  // lane = source block
    u64 lst[16];
#pragma unroll
    for (int j = 0; j < NSEL; j++) lst[j] = cb[j];          // sorted descending
    u64 won = 0ULL;
#pragma unroll
    for (int r = 0; r < NSEL; r++) {
      u64 g = wave_max64(lst[0]);
      if (lane == r) won = g;
      if (lst[0] == g) {               // unique winner (distinct keys)
#pragma unroll
        for (int i = 0; i < NSEL - 1; i++) lst[i] = lst[i + 1];
        lst[NSEL - 1] = 0ULL;
      }
    }
    if (lane < NSEL) {
      u32 e = 0xFFFFFFFFu - (u32)(won & 0xFFFFFFFFu);
      s_idx[lane] = (int)e;
      if (blk == 0) att_out[b * NSEL + lane] = att[b * HW + (int)e];  // bit-exact
    }
  }
  __syncthreads();

  // ---- patch extraction: this block's 3072 float4 of its batch ----
  float4* out4 = (float4*)out;
#pragma unroll
  for (int it = 0; it < 12; it++) {
    const int fi = blk * 3072 + it * 256 + tid;   // within-batch float4 idx
    const int pc = fi >> 12;                      // channel-patch 0..47
    const int n = pc / 3;                         // patch 0..15
    const int c = pc - n * 3;                     // channel 0..2
    const int r = (fi >> 5) & 127;                // row in patch
    const int q = fi & 31;                        // float4 in row
    const int e = s_idx[n];
    const int row = (e >> 8) * 8 - 60 + r;
    const int col = (e & 255) * 8 - 60 + (q << 2);
    float4 v = make_float4(0.f, 0.f, 0.f, 0.f);
    // col is a multiple of 4 -> float4 fully in-bounds or fully out
    if ((u32)row < (u32)HH && (u32)col < (u32)HH) {
      v = *reinterpret_cast<const float4*>(
          xh + (((size_t)(b * NC + c)) << 22) + ((size_t)row << 11) + col);
    }
    out4[(size_t)b * 196608 + fi] = v;
  }
}

extern "C" void kernel_launch(void* const* d_in, const int* in_sizes, int n_in,
                              void* d_out, int out_size, void* d_ws, size_t ws_size,
                              hipStream_t stream) {
  (void)in_sizes; (void)n_in; (void)out_size; (void)ws_size;
  // inputs: 0=x_low (unused, shape-only), 1=x_high, 2=attention, 3=noise_u
  const float* x_high = (const float*)d_in[1];
  const float* att    = (const float*)d_in[2];
  const float* noise  = (const float*)d_in[3];
  float* out = (float*)d_out;
  float* att_out = out + (size_t)NB * NSEL * NC * 128 * 128;   // 6291456

  char* ws = (char*)d_ws;
  u32* bar  = (u32*)ws;                 // 8 u32 barrier counters (64 B incl pad)
  u64* cand = (u64*)(ws + 64);          // 512 blocks * 16 u64 = 64 KiB

  // zero the barrier counters every replay (graph-legal async memset)
  hipMemsetAsync(bar, 0, NB * sizeof(u32), stream);
  fused_sample_patches<<<dim3(NB * 64), dim3(256), 0, stream>>>(
      x_high, att, noise, out, att_out, cand, bar);
}

// Round 5
// 32.168 us; speedup vs baseline: 5.6061x; 2.7821x over previous
//
#include <hip/hip_runtime.h>

typedef unsigned long long u64;
typedef unsigned int u32;

#define HW 65536            // 256*256 attention positions per batch
#define NB 8                // batch
#define NSEL 16             // top-k
#define NC 3
#define HH 2048             // x_high H=W

// surrogate key: order(log a - log(-log u)) == order(a / (-log2 u)).
__device__ __forceinline__ u32 wkey(float a, float u) {
  float v = __builtin_amdgcn_logf(u);            // log2(u) < 0
  float w = a * __builtin_amdgcn_rcpf(-v);       // a / (-log2 u) > 0
  return __float_as_uint(w);                     // positive floats order as uints
}

__device__ __forceinline__ u64 wave_max64(u64 k) {
#pragma unroll
  for (int off = 1; off < 64; off <<= 1) {
    u32 lo = __shfl_xor((u32)k, off, 64);
    u32 hi = __shfl_xor((u32)(k >> 32), off, 64);
    u64 o = ((u64)hi << 32) | lo;
    if (o > k) k = o;
  }
  return k;
}

#define CMPSWAP(a, b) { if ((b) > (a)) { u64 t_ = (a); (a) = (b); (b) = t_; } }

// Kernel A: 512 blocks x 256 thr. Block-local top-16 of its 1024 elements,
// written as a SORTED 16-list to cand[blockIdx]. No cross-block sync.
__global__ __launch_bounds__(256) void scan_topk(
    const float* __restrict__ att, const float* __restrict__ noise,
    u64* __restrict__ cand) {
  const int tid = threadIdx.x;
  const int lane = tid & 63;
  const int wave = tid >> 6;
  const int b = blockIdx.x >> 6;       // batch
  const int blk = blockIdx.x & 63;     // block within batch (1024 elems)

  __shared__ u64 s_wtop[64];           // 4 waves x 16

  // per-lane sorted-4 of its 4 elements (coalesced loads)
  const int ebase = blk * 1024 + wave * 256;
  u64 k4[4];
#pragma unroll
  for (int j = 0; j < 4; j++) {
    const int e = ebase + (j << 6) + lane;
    const int gi = b * HW + e;
    k4[j] = ((u64)wkey(att[gi], noise[gi]) << 32) | (0xFFFFFFFFu - (u32)e);
  }
  CMPSWAP(k4[0], k4[1]); CMPSWAP(k4[2], k4[3]);
  CMPSWAP(k4[0], k4[2]); CMPSWAP(k4[1], k4[3]);
  CMPSWAP(k4[1], k4[2]);

  // per-wave top-16 -> LDS (16 extraction rounds; keys globally distinct)
#pragma unroll
  for (int r = 0; r < NSEL; r++) {
    u64 g = wave_max64(k4[0]);
    if (k4[0] == g) {                  // exactly one winning lane
      s_wtop[wave * 16 + r] = g;
      k4[0] = k4[1]; k4[1] = k4[2]; k4[2] = k4[3]; k4[3] = 0ULL;
    }
  }
  __syncthreads();

  // wave 0: merge 64 -> sorted block top-16 -> cand
  if (wave == 0) {
    u64 kk = s_wtop[lane];
#pragma unroll
    for (int r = 0; r < NSEL; r++) {
      u64 g = wave_max64(kk);
      if (kk == g) {
        cand[(size_t)blockIdx.x * NSEL + r] = g;   // sorted position r
        kk = 0ULL;
      }
    }
  }
}

// Kernel B: 768 blocks x 256 thr. Each block: wave 0 redundantly merges its
// batch's 64 sorted 16-lists -> s_idx, then all waves copy one half-patch.
__global__ __launch_bounds__(256) void merge_patch(
    const float* __restrict__ xh, const float* __restrict__ att,
    const u64* __restrict__ cand, float* __restrict__ out,
    float* __restrict__ att_out) {
  const int blk = blockIdx.x;       // [0, 768)
  const int h = blk & 1;            // top/bottom half (64 rows)
  const int pairc = blk >> 1;       // (b*16+n)*3 + c
  const int c = pairc % 3;
  const int bn = pairc / 3;         // b*16 + n
  const int b = bn >> 4;
  const int n = bn & 15;
  const int tid = threadIdx.x;
  const int lane = tid & 63;
  const int wave = tid >> 6;

  __shared__ int s_idx[NSEL];

  if (wave == 0) {
    // lane = source block; its sorted 16-list
    const u64* cb = cand + (size_t)(b * 64 + lane) * NSEL;
    u64 lst[NSEL];
#pragma unroll
    for (int j = 0; j < NSEL; j++) lst[j] = cb[j];
    u64 won = 0ULL;
#pragma unroll
    for (int r = 0; r < NSEL; r++) {
      u64 g = wave_max64(lst[0]);
      if (lane == r) won = g;
      if (lst[0] == g) {               // unique winner (distinct keys)
#pragma unroll
        for (int i = 0; i < NSEL - 1; i++) lst[i] = lst[i + 1];
        lst[NSEL - 1] = 0ULL;
      }
    }
    if (lane < NSEL) {
      u32 e = 0xFFFFFFFFu - (u32)(won & 0xFFFFFFFFu);
      s_idx[lane] = (int)e;
      if (pairc == b * 48 && h == 0)   // one block per batch writes att_out
        att_out[b * NSEL + lane] = att[b * HW + (int)e];   // bit-exact gather
    }
  }
  __syncthreads();

  const int e = s_idx[n];
  const int sr = e >> 8;
  const int sc = e & 255;
  const int r0 = sr * 8 - 60 + h * 64;   // unpadded row start for this half
  const int c0 = sc * 8 - 60;            // unpadded col start (multiple of 4)
  const float* src = xh + ((size_t)(b * NC + c) << 22);
  float* dst = out + (size_t)pairc * (128 * 128) + (size_t)h * (64 * 128);

#pragma unroll
  for (int i = tid; i < 64 * 32; i += 256) {  // 2048 float4 per half-patch
    const int pr = i >> 5;          // row within half
    const int q = i & 31;           // float4 index within row
    const int r = r0 + pr;
    const int cc = c0 + (q << 2);
    float4 v = make_float4(0.f, 0.f, 0.f, 0.f);
    // cc multiple of 4 -> float4 fully in-bounds or fully out
    if ((u32)r < (u32)HH && (u32)cc < (u32)HH) {
      v = *reinterpret_cast<const float4*>(src + ((size_t)r << 11) + cc);
    }
    *reinterpret_cast<float4*>(dst + ((size_t)i << 2)) = v;
  }
}

extern "C" void kernel_launch(void* const* d_in, const int* in_sizes, int n_in,
                              void* d_out, int out_size, void* d_ws, size_t ws_size,
                              hipStream_t stream) {
  (void)in_sizes; (void)n_in; (void)out_size; (void)ws_size;
  // inputs: 0=x_low (unused, shape-only), 1=x_high, 2=attention, 3=noise_u
  const float* x_high = (const float*)d_in[1];
  const float* att    = (const float*)d_in[2];
  const float* noise  = (const float*)d_in[3];
  float* out = (float*)d_out;
  float* att_out = out + (size_t)NB * NSEL * NC * 128 * 128;   // 6291456

  u64* cand = (u64*)d_ws;               // 512 blocks * 16 u64 = 64 KiB

  scan_topk<<<dim3(NB * 64), dim3(256), 0, stream>>>(att, noise, cand);
  merge_patch<<<dim3(NB * NSEL * NC * 2), dim3(256), 0, stream>>>(
      x_high, att, cand, out, att_out);
}